// Round 1
// 440.226 us; speedup vs baseline: 1.0091x; 1.0091x over previous
//
#include <hip/hip_runtime.h>

// AdaptiveLayer: per-(b,f) sequential scan over T.
//   out[b,t,f] = max(x[b,t,f] - adapt, 0)
//   adapt      = (adapt + 0.1*out) * 0.9
// x: [B=32, T=512, F=4096] f32. adaptation: [1, F] f32 (initial state).
// Memory-bound: 268 MB in + 268 MB out -> ~85 us roofline at 6.3 TB/s.
//
// R1: float2 across f (512 B/wave-inst, G13 sweet spot) + explicit
// double-buffered prefetch (two NAMED buffers A/B, static indexing only --
// runtime-indexed arrays spill to scratch, rule #20). Keeps ~16 KB/CU of
// reads in flight at ~100% duty vs ~9.2 KB needed by Little's law.

#define AB 32
#define AT 512
#define AF 4096
#define F2 (AF / 2)            // 2048 float2 per row
#define ADAPT_RATE 0.1f
#define RECOVERY_RATE 0.1f

__global__ __launch_bounds__(256) void AdaptiveLayer_kernel(
    const float* __restrict__ x,
    const float* __restrict__ adaptation,
    float* __restrict__ out) {
    // One thread per (b, f-pair) chain. Consecutive tids -> consecutive f2:
    // coalesced 512 B/wave loads at each t (stride F between t steps).
    const int tid = blockIdx.x * blockDim.x + threadIdx.x;   // 0 .. B*F/2-1
    const int b  = tid >> 11;            // tid / 2048
    const int f2 = tid & (F2 - 1);       // tid % 2048

    const size_t base2 = (size_t)b * (size_t)AT * (size_t)F2 + (size_t)f2;
    const float2* __restrict__ xp = reinterpret_cast<const float2*>(x) + base2;
    float2* __restrict__ op       = reinterpret_cast<float2*>(out) + base2;

    float2 adapt = reinterpret_cast<const float2*>(adaptation)[f2];

    // Two named prefetch buffers; all indices compile-time constant.
    float2 bufA[8], bufB[8];

    // Prologue: prefetch t = 0..7 into A.
    #pragma unroll
    for (int j = 0; j < 8; ++j) bufA[j] = xp[(size_t)j * F2];

    #pragma unroll 1
    for (int t = 0; t < AT; t += 16) {
        // Prefetch t+8..t+15 into B while A's recurrence runs.
        #pragma unroll
        for (int j = 0; j < 8; ++j) bufB[j] = xp[(size_t)(t + 8 + j) * F2];

        // Consume A (serial recurrence; x/y are two independent chains).
        #pragma unroll
        for (int j = 0; j < 8; ++j) {
            float ox = fmaxf(bufA[j].x - adapt.x, 0.0f);
            float oy = fmaxf(bufA[j].y - adapt.y, 0.0f);
            op[(size_t)(t + j) * F2] = make_float2(ox, oy);
            adapt.x = (adapt.x + ADAPT_RATE * ox) * (1.0f - RECOVERY_RATE);
            adapt.y = (adapt.y + ADAPT_RATE * oy) * (1.0f - RECOVERY_RATE);
        }

        // Prefetch t+16..t+23 into A while B's recurrence runs.
        if (t + 16 < AT) {
            #pragma unroll
            for (int j = 0; j < 8; ++j) bufA[j] = xp[(size_t)(t + 16 + j) * F2];
        }

        // Consume B.
        #pragma unroll
        for (int j = 0; j < 8; ++j) {
            float ox = fmaxf(bufB[j].x - adapt.x, 0.0f);
            float oy = fmaxf(bufB[j].y - adapt.y, 0.0f);
            op[(size_t)(t + 8 + j) * F2] = make_float2(ox, oy);
            adapt.x = (adapt.x + ADAPT_RATE * ox) * (1.0f - RECOVERY_RATE);
            adapt.y = (adapt.y + ADAPT_RATE * oy) * (1.0f - RECOVERY_RATE);
        }
    }
}

extern "C" void kernel_launch(void* const* d_in, const int* in_sizes, int n_in,
                              void* d_out, int out_size, void* d_ws, size_t ws_size,
                              hipStream_t stream) {
    const float* x          = (const float*)d_in[0];   // [B, T, F]
    const float* adaptation = (const float*)d_in[1];   // [1, F]
    float* out              = (float*)d_out;           // [B, T, F]

    const int n_chains = AB * F2;                      // 65536 threads (f-pairs)
    const int block = 256;
    const int grid = n_chains / block;                 // 256 blocks -> 1/CU, 4 waves/CU

    AdaptiveLayer_kernel<<<grid, block, 0, stream>>>(x, adaptation, out);
}

// Round 3
// 422.589 us; speedup vs baseline: 1.0512x; 1.0417x over previous
//
#include <hip/hip_runtime.h>

// AdaptiveLayer: per-(b,f) sequential scan over T.
//   out[b,t,f] = max(x[b,t,f] - adapt, 0)
//   adapt      = (adapt + 0.1*out) * 0.9
// x: [B=32, T=512, F=4096] f32. adaptation: [1, F] f32 (initial state).
// Memory-bound: 268 MB in + 268 MB out -> ~85 us roofline at 6.3 TB/s.
//
// R3 = R2 with the compile fix: __builtin_nontemporal_* requires a NATIVE
// clang vector type, not HIP_vector_type<float,4>. Use ext_vector_type(4).
// R2 rationale: float4 lanes (16 B/lane -- the granularity the 6.29 TB/s
// copy ceiling was measured at, m13) + named A/B double-buffer prefetch
// (rule #20: static indices only) + nontemporal load/store (536 MB
// touch-once streams thrash the 256 MB L3).
// 32768 threads = 256 blocks x 128 -> 1 block/CU, 2 waves/CU; in-flight
// reads 2 x 8 KB = 16 KB/CU >= ~5 KB Little's-law requirement.

#define AB 32
#define AT 512
#define AF 4096
#define F4 (AF / 4)            // 1024 float4 per row
#define ADAPT_RATE 0.1f
#define RECOVERY_RATE 0.1f

typedef float f32x4 __attribute__((ext_vector_type(4)));

__global__ __launch_bounds__(128) void AdaptiveLayer_kernel(
    const float* __restrict__ x,
    const float* __restrict__ adaptation,
    float* __restrict__ out) {
    const int tid = blockIdx.x * blockDim.x + threadIdx.x;   // 0 .. B*F/4-1
    const int b  = tid >> 10;            // tid / 1024
    const int f4 = tid & (F4 - 1);       // tid % 1024

    const size_t base4 = (size_t)b * (size_t)AT * (size_t)F4 + (size_t)f4;
    const f32x4* __restrict__ xp = reinterpret_cast<const f32x4*>(x) + base4;
    f32x4* __restrict__ op       = reinterpret_cast<f32x4*>(out) + base4;

    f32x4 adapt = reinterpret_cast<const f32x4*>(adaptation)[f4];

    // Two named prefetch buffers; all indices compile-time constant.
    f32x4 bufA[8], bufB[8];

    // Prologue: prefetch t = 0..7 into A.
    #pragma unroll
    for (int j = 0; j < 8; ++j)
        bufA[j] = __builtin_nontemporal_load(xp + (size_t)j * F4);

    #pragma unroll 1
    for (int t = 0; t < AT; t += 16) {
        // Prefetch t+8..t+15 into B while A's recurrence runs.
        #pragma unroll
        for (int j = 0; j < 8; ++j)
            bufB[j] = __builtin_nontemporal_load(xp + (size_t)(t + 8 + j) * F4);

        // Consume A (serial recurrence; 4 independent chains per thread).
        #pragma unroll
        for (int j = 0; j < 8; ++j) {
            f32x4 v = bufA[j];
            f32x4 o;
            o.x = fmaxf(v.x - adapt.x, 0.0f);
            o.y = fmaxf(v.y - adapt.y, 0.0f);
            o.z = fmaxf(v.z - adapt.z, 0.0f);
            o.w = fmaxf(v.w - adapt.w, 0.0f);
            __builtin_nontemporal_store(o, op + (size_t)(t + j) * F4);
            adapt.x = (adapt.x + ADAPT_RATE * o.x) * (1.0f - RECOVERY_RATE);
            adapt.y = (adapt.y + ADAPT_RATE * o.y) * (1.0f - RECOVERY_RATE);
            adapt.z = (adapt.z + ADAPT_RATE * o.z) * (1.0f - RECOVERY_RATE);
            adapt.w = (adapt.w + ADAPT_RATE * o.w) * (1.0f - RECOVERY_RATE);
        }

        // Prefetch t+16..t+23 into A while B's recurrence runs.
        if (t + 16 < AT) {
            #pragma unroll
            for (int j = 0; j < 8; ++j)
                bufA[j] = __builtin_nontemporal_load(xp + (size_t)(t + 16 + j) * F4);
        }

        // Consume B.
        #pragma unroll
        for (int j = 0; j < 8; ++j) {
            f32x4 v = bufB[j];
            f32x4 o;
            o.x = fmaxf(v.x - adapt.x, 0.0f);
            o.y = fmaxf(v.y - adapt.y, 0.0f);
            o.z = fmaxf(v.z - adapt.z, 0.0f);
            o.w = fmaxf(v.w - adapt.w, 0.0f);
            __builtin_nontemporal_store(o, op + (size_t)(t + 8 + j) * F4);
            adapt.x = (adapt.x + ADAPT_RATE * o.x) * (1.0f - RECOVERY_RATE);
            adapt.y = (adapt.y + ADAPT_RATE * o.y) * (1.0f - RECOVERY_RATE);
            adapt.z = (adapt.z + ADAPT_RATE * o.z) * (1.0f - RECOVERY_RATE);
            adapt.w = (adapt.w + ADAPT_RATE * o.w) * (1.0f - RECOVERY_RATE);
        }
    }
}

extern "C" void kernel_launch(void* const* d_in, const int* in_sizes, int n_in,
                              void* d_out, int out_size, void* d_ws, size_t ws_size,
                              hipStream_t stream) {
    const float* x          = (const float*)d_in[0];   // [B, T, F]
    const float* adaptation = (const float*)d_in[1];   // [1, F]
    float* out              = (float*)d_out;           // [B, T, F]

    const int n_chains = AB * F4;                      // 32768 threads (f-quads)
    const int block = 128;
    const int grid = n_chains / block;                 // 256 blocks -> 1/CU

    AdaptiveLayer_kernel<<<grid, block, 0, stream>>>(x, adaptation, out);
}